// Round 2
// baseline (536.685 us; speedup 1.0000x reference)
//
#include <hip/hip_runtime.h>
#include <hip/hip_bf16.h>

// Problem constants (B,C,T,H,W = 2,64,8,48,48)
#define CC 64
#define TT 8
#define PP 2304        // 48*48
#define C2 32
#define BT 16          // B*T
#define TQ 64
#define SCALE 0.17677669529663687f   // 1/sqrt(32)

// x element (b,c,t,p): ((b*CC + c)*TT + t)*PP + p

// ---------------------------------------------------------------------------
// Path A, k1: theta/phi = per-slice 1x1 conv of x. grid (BT, 9), block 256.
// ---------------------------------------------------------------------------
__global__ __launch_bounds__(256) void k_thetaphi(
    const float* __restrict__ x, const float* __restrict__ tw,
    const float* __restrict__ pw, float* __restrict__ theta_o,
    float* __restrict__ phi_o) {
  const int bt = blockIdx.x;
  const int b = bt >> 3, t = bt & 7;
  const int p = blockIdx.y * 256 + threadIdx.x;

  __shared__ float tws[C2 * CC];
  __shared__ float pws[C2 * CC];
  for (int i = threadIdx.x; i < C2 * CC; i += 256) {
    tws[i] = tw[t * C2 * CC + i];
    pws[i] = pw[t * C2 * CC + i];
  }
  __syncthreads();

  float xr[CC];
#pragma unroll
  for (int c = 0; c < CC; c++)
    xr[c] = x[((size_t)(b * CC + c) * TT + t) * PP + p];

  for (int c2 = 0; c2 < C2; c2++) {
    float at = 0.f, ap = 0.f;
#pragma unroll
    for (int c = 0; c < CC; c++) {
      at += tws[c2 * CC + c] * xr[c];   // uniform addr -> broadcast
      ap += pws[c2 * CC + c] * xr[c];
    }
    theta_o[(size_t)(bt * C2 + c2) * PP + p] = at;
    phi_o[(size_t)(bt * C2 + c2) * PP + p] = ap;
  }
}

// ---------------------------------------------------------------------------
// Path A, k2: flash attention partials (plain sums; exp clamped, no max).
// grid (BT, 9, NQ), block 256. partial: [qc][bt][c(0..64)][p], c==64 is l.
// ---------------------------------------------------------------------------
__global__ __launch_bounds__(256) void k_attn(
    const float* __restrict__ x, const float* __restrict__ theta,
    const float* __restrict__ phi, float* __restrict__ partial, int nsub) {
  const int bt = blockIdx.x;
  const int b = bt >> 3, t = bt & 7;
  const int p = blockIdx.y * 256 + threadIdx.x;
  const int qc = blockIdx.z;

  __shared__ __align__(16) float phi_s[TQ][C2 + 4];  // stride 36 (16B rows)
  __shared__ __align__(16) float x_s[TQ][CC + 4];    // stride 68

  float th[C2];
#pragma unroll
  for (int c2 = 0; c2 < C2; c2++)
    th[c2] = theta[(size_t)(bt * C2 + c2) * PP + p];

  float acc[CC];
#pragma unroll
  for (int c = 0; c < CC; c++) acc[c] = 0.f;
  float l = 0.f;

  const int q0base = qc * nsub * TQ;
  for (int sub = 0; sub < nsub; sub++) {
    const int q0 = q0base + sub * TQ;
    __syncthreads();
    for (int i = threadIdx.x; i < C2 * TQ; i += 256) {
      int c2 = i >> 6, q = i & 63;
      phi_s[q][c2] = phi[(size_t)(bt * C2 + c2) * PP + q0 + q];
    }
    for (int i = threadIdx.x; i < CC * TQ; i += 256) {
      int c = i >> 6, q = i & 63;
      x_s[q][c] = x[((size_t)(b * CC + c) * TT + t) * PP + q0 + q];
    }
    __syncthreads();

    for (int q = 0; q < TQ; q++) {
      const float4* ph = (const float4*)&phi_s[q][0];  // broadcast
      float s = 0.f;
#pragma unroll
      for (int j = 0; j < 8; j++) {
        float4 v = ph[j];
        s += th[4 * j] * v.x + th[4 * j + 1] * v.y + th[4 * j + 2] * v.z +
             th[4 * j + 3] * v.w;
      }
      float wgt = __expf(fminf(s * SCALE, 60.f));
      l += wgt;
      const float4* xr4 = (const float4*)&x_s[q][0];  // broadcast
#pragma unroll
      for (int j = 0; j < 16; j++) {
        float4 v = xr4[j];
        acc[4 * j] += wgt * v.x;
        acc[4 * j + 1] += wgt * v.y;
        acc[4 * j + 2] += wgt * v.z;
        acc[4 * j + 3] += wgt * v.w;
      }
    }
  }

  float* base = partial + ((size_t)(qc * BT + bt) * 65) * PP + p;
#pragma unroll
  for (int c = 0; c < CC; c++) base[(size_t)c * PP] = acc[c];
  base[(size_t)64 * PP] = l;
}

// ---------------------------------------------------------------------------
// Path A, k3: reduce partials, normalize, out_w, residual. grid (BT, 9).
// ---------------------------------------------------------------------------
__global__ __launch_bounds__(256) void k_out(
    const float* __restrict__ x, const float* __restrict__ ow,
    const float* __restrict__ partial, float* __restrict__ out, int NQ) {
  const int bt = blockIdx.x;
  const int b = bt >> 3, t = bt & 7;
  const int p = blockIdx.y * 256 + threadIdx.x;

  __shared__ __align__(16) float ow_s[CC * CC];
  for (int i = threadIdx.x; i < CC * CC; i += 256) ow_s[i] = ow[i];
  __syncthreads();

  float f[CC];
#pragma unroll
  for (int c = 0; c < CC; c++) f[c] = 0.f;
  float l = 0.f;
  for (int qc = 0; qc < NQ; qc++) {
    const float* base = partial + ((size_t)(qc * BT + bt) * 65) * PP + p;
#pragma unroll
    for (int c = 0; c < CC; c++) f[c] += base[(size_t)c * PP];
    l += base[(size_t)64 * PP];
  }
  const float inv = 1.f / l;
#pragma unroll
  for (int c = 0; c < CC; c++) f[c] *= inv;

  for (int co = 0; co < CC; co++) {
    const float4* wr = (const float4*)&ow_s[co * CC];  // broadcast
    float o = 0.f;
#pragma unroll
    for (int j = 0; j < 16; j++) {
      float4 v = wr[j];
      o += v.x * f[4 * j] + v.y * f[4 * j + 1] + v.z * f[4 * j + 2] +
           v.w * f[4 * j + 3];
    }
    size_t idx = ((size_t)(b * CC + co) * TT + t) * PP + p;
    out[idx] = o + x[idx];
  }
}

// ---------------------------------------------------------------------------
// Path B: fully fused, ZERO workspace. grid (BT, 9), block 256.
// theta in registers; phi recomputed per block from LDS x-tiles (+8% MACs).
// ---------------------------------------------------------------------------
__global__ __launch_bounds__(256) void k_fused(
    const float* __restrict__ x, const float* __restrict__ tw,
    const float* __restrict__ pw, const float* __restrict__ ow,
    float* __restrict__ out) {
  const int bt = blockIdx.x;
  const int b = bt >> 3, t = bt & 7;
  const int tid = threadIdx.x;
  const int p = blockIdx.y * 256 + tid;

  __shared__ float tw_s[C2 * CC];                    // [c2][c]
  __shared__ float pw_t[CC][C2 + 1];                 // transposed: [c][c2]
  __shared__ float ow_s[CC * CC];                    // [co][c]
  __shared__ __align__(16) float x_s[TQ][CC + 4];    // [q][c] stride 68
  __shared__ __align__(16) float phi_s[TQ][C2 + 4];  // [q][c2] stride 36

  for (int i = tid; i < C2 * CC; i += 256) {
    tw_s[i] = tw[t * C2 * CC + i];
    int c2 = i >> 6, c = i & 63;
    pw_t[c][c2] = pw[t * C2 * CC + i];
  }
  for (int i = tid; i < CC * CC; i += 256) ow_s[i] = ow[i];
  __syncthreads();

  const size_t xbase = (size_t)b * CC * TT * PP + (size_t)t * PP;

  // theta for this thread's p
  float th[C2];
#pragma unroll
  for (int c2 = 0; c2 < C2; c2++) th[c2] = 0.f;
  for (int c = 0; c < CC; c++) {
    float xc = x[xbase + (size_t)c * (TT * PP) + p];
#pragma unroll
    for (int c2 = 0; c2 < C2; c2++) th[c2] += tw_s[c2 * CC + c] * xc;
  }

  float acc[CC];
#pragma unroll
  for (int c = 0; c < CC; c++) acc[c] = 0.f;
  float l = 0.f;

  for (int q0 = 0; q0 < PP; q0 += TQ) {
    __syncthreads();
#pragma unroll
    for (int k = 0; k < 16; k++) {   // stage x tile 64c x 64q
      int i = tid + k * 256;
      int c = i >> 6, q = i & 63;
      x_s[q][c] = x[xbase + (size_t)c * (TT * PP) + q0 + q];
    }
    __syncthreads();
#pragma unroll
    for (int k = 0; k < 8; k++) {    // phi tile 32c2 x 64q cooperatively
      int i = tid + k * 256;
      int c2 = i & 31, q = i >> 5;
      float s = 0.f;
#pragma unroll 8
      for (int c = 0; c < CC; c++) s += pw_t[c][c2] * x_s[q][c];
      phi_s[q][c2] = s;
    }
    __syncthreads();

    for (int q = 0; q < TQ; q++) {
      const float4* ph = (const float4*)&phi_s[q][0];  // broadcast
      float s = 0.f;
#pragma unroll
      for (int j = 0; j < 8; j++) {
        float4 v = ph[j];
        s += th[4 * j] * v.x + th[4 * j + 1] * v.y + th[4 * j + 2] * v.z +
             th[4 * j + 3] * v.w;
      }
      float wgt = __expf(fminf(s * SCALE, 60.f));
      l += wgt;
      const float4* xr4 = (const float4*)&x_s[q][0];  // broadcast
#pragma unroll
      for (int j = 0; j < 16; j++) {
        float4 v = xr4[j];
        acc[4 * j] += wgt * v.x;
        acc[4 * j + 1] += wgt * v.y;
        acc[4 * j + 2] += wgt * v.z;
        acc[4 * j + 3] += wgt * v.w;
      }
    }
  }

  const float inv = 1.f / l;
#pragma unroll
  for (int c = 0; c < CC; c++) acc[c] *= inv;

  for (int co = 0; co < CC; co++) {
    const float4* wr = (const float4*)&ow_s[co * CC];  // broadcast
    float o = 0.f;
#pragma unroll
    for (int j = 0; j < 16; j++) {
      float4 v = wr[j];
      o += v.x * acc[4 * j] + v.y * acc[4 * j + 1] + v.z * acc[4 * j + 2] +
           v.w * acc[4 * j + 3];
    }
    size_t idx = xbase + (size_t)co * (TT * PP) + p;
    out[idx] = o + x[idx];
  }
}

extern "C" void kernel_launch(void* const* d_in, const int* in_sizes, int n_in,
                              void* d_out, int out_size, void* d_ws,
                              size_t ws_size, hipStream_t stream) {
  (void)in_sizes; (void)n_in; (void)out_size;
  const float* x = (const float*)d_in[0];
  const float* tw = (const float*)d_in[1];
  const float* pw = (const float*)d_in[2];
  const float* ow = (const float*)d_in[3];
  float* out = (float*)d_out;

  const size_t base = (size_t)2 * BT * C2 * PP * sizeof(float);
  const size_t per_nq = (size_t)BT * 65 * PP * sizeof(float);
  int NQ = 0;
  if (ws_size >= base + 4 * per_nq) NQ = 4;
  else if (ws_size >= base + 2 * per_nq) NQ = 2;
  else if (ws_size >= base + 1 * per_nq) NQ = 1;

  if (NQ > 0) {
    float* theta_ws = (float*)d_ws;
    float* phi_ws = theta_ws + (size_t)BT * C2 * PP;
    float* partial = phi_ws + (size_t)BT * C2 * PP;
    const int nsub = 36 / NQ;
    k_thetaphi<<<dim3(BT, 9), 256, 0, stream>>>(x, tw, pw, theta_ws, phi_ws);
    k_attn<<<dim3(BT, 9, NQ), 256, 0, stream>>>(x, theta_ws, phi_ws, partial,
                                                nsub);
    k_out<<<dim3(BT, 9), 256, 0, stream>>>(x, ow, partial, out, NQ);
  } else {
    k_fused<<<dim3(BT, 9), 256, 0, stream>>>(x, tw, pw, ow, out);
  }
}

// Round 3
// 248.410 us; speedup vs baseline: 2.1605x; 2.1605x over previous
//
#include <hip/hip_runtime.h>
#include <hip/hip_bf16.h>

// Problem constants (B,C,T,H,W = 2,64,8,48,48)
#define CC 64
#define TT 8
#define PP 2304        // 48*48
#define C2 32
#define BT 16          // B*T
// log2(e)/sqrt(32): folds softmax scale AND exp->exp2 into theta pre-scale
#define SCALE2 0.25503486f

typedef __attribute__((ext_vector_type(8))) short short8;   // 8 bf16 (4 VGPRs)
typedef __attribute__((ext_vector_type(4))) float float4v;  // MFMA C/D frag

#if __has_builtin(__builtin_amdgcn_exp2f)
#define EXP2(v) __builtin_amdgcn_exp2f(v)
#else
#define EXP2(v) __expf((v)*0.6931471805599453f)
#endif

static __device__ __forceinline__ short f2bf(float f) {
  __hip_bfloat16 h = __float2bfloat16(f);
  return *reinterpret_cast<const short*>(&h);
}

// ---------------------------------------------------------------------------
// k_prep: theta (pre-scaled) / phi as [bt][p][32] bf16, x cast to [bt][c][q]
// bf16. grid (9, BT), block 256, one thread per p.
// ---------------------------------------------------------------------------
__global__ __launch_bounds__(256) void k_prep(
    const float* __restrict__ x, const float* __restrict__ tw,
    const float* __restrict__ pw, short* __restrict__ thb,
    short* __restrict__ phb, short* __restrict__ xb) {
  const int bt = blockIdx.y;
  const int b = bt >> 3, t = bt & 7;
  const int p = blockIdx.x * 256 + threadIdx.x;

  __shared__ float tws[C2 * CC];
  __shared__ float pws[C2 * CC];
  for (int i = threadIdx.x; i < C2 * CC; i += 256) {
    tws[i] = tw[t * C2 * CC + i];
    pws[i] = pw[t * C2 * CC + i];
  }
  __syncthreads();

  float xr[CC];
#pragma unroll
  for (int c = 0; c < CC; c++) {
    xr[c] = x[((size_t)(b * CC + c) * TT + t) * PP + p];
    xb[(size_t)(bt * CC + c) * PP + p] = f2bf(xr[c]);  // coalesced b16 store
  }

  float th[C2], ph[C2];
#pragma unroll
  for (int c2 = 0; c2 < C2; c2++) { th[c2] = 0.f; ph[c2] = 0.f; }
  for (int c = 0; c < CC; c++) {
#pragma unroll
    for (int c2 = 0; c2 < C2; c2++) {
      th[c2] += tws[c2 * CC + c] * xr[c];  // uniform addr -> broadcast
      ph[c2] += pws[c2 * CC + c] * xr[c];
    }
  }

  const size_t rbase = ((size_t)bt * PP + p) * C2;
#pragma unroll
  for (int k = 0; k < 4; k++) {
    short8 tv, pv;
#pragma unroll
    for (int j = 0; j < 8; j++) {
      tv[j] = f2bf(th[k * 8 + j] * SCALE2);
      pv[j] = f2bf(ph[k * 8 + j]);
    }
    *reinterpret_cast<short8*>(thb + rbase + k * 8) = tv;
    *reinterpret_cast<short8*>(phb + rbase + k * 8) = pv;
  }
}

// ---------------------------------------------------------------------------
// k_attn_mfma: flash attention + out-proj + residual, all MFMA.
// grid (36, BT), block 256 (4 waves). Wave w owns query rows
// m0 = ptile*64 + w*16 .. +15. Main loop over 36 key tiles of 64.
// No __syncthreads in the main loop: the W round trip is per-wave LDS.
// ---------------------------------------------------------------------------
__global__ __launch_bounds__(256, 2) void k_attn_mfma(
    const float* __restrict__ x, const short* __restrict__ thb,
    const short* __restrict__ phb, const short* __restrict__ xb,
    const float* __restrict__ ow, float* __restrict__ out) {
  const int ptile = blockIdx.x;
  const int bt = blockIdx.y;
  const int b = bt >> 3, t = bt & 7;
  const int tid = threadIdx.x;
  const int wv = tid >> 6, lane = tid & 63;
  const int quad = lane >> 4, l15 = lane & 15;

  __shared__ __align__(16) short W_lds[4][16][72];  // per-wave [row][key+pad]
  __shared__ __align__(16) float out_s[CC][68];     // [co][p+pad]

  // theta A-frag: A[m=l15][k=quad*8+j], rows fixed all kernel
  const short8 a_th = *reinterpret_cast<const short8*>(
      thb + ((size_t)bt * PP + ptile * 64 + wv * 16 + l15) * C2 + quad * 8);

  const short* phbase = phb + (size_t)bt * PP * C2;
  const short* xbase = xb + (size_t)bt * CC * PP;

  const float4v zero = {0.f, 0.f, 0.f, 0.f};
  float4v O[4] = {zero, zero, zero, zero};  // [ch ntile], rows=quad*4+reg
  float4v l_acc = zero;

  // B-frag prefetch registers (tile kt=0)
  short8 bphi[4], bx[8];
#pragma unroll
  for (int nt = 0; nt < 4; nt++)
    bphi[nt] = *reinterpret_cast<const short8*>(
        phbase + (size_t)(nt * 16 + l15) * C2 + quad * 8);
#pragma unroll
  for (int nt = 0; nt < 4; nt++)
#pragma unroll
    for (int ks = 0; ks < 2; ks++)
      bx[nt * 2 + ks] = *reinterpret_cast<const short8*>(
          xbase + (size_t)(nt * 16 + l15) * PP + ks * 32 + quad * 8);

  for (int kt = 0; kt < 36; kt++) {
    // ---- S = theta . phi^T  (pre-scaled: S is already the exp2 argument)
    float4v s_acc[4];
#pragma unroll
    for (int nt = 0; nt < 4; nt++)
      s_acc[nt] = __builtin_amdgcn_mfma_f32_16x16x32_bf16(a_th, bphi[nt], zero,
                                                          0, 0, 0);
    // ---- prefetch next key tile's B-frags (overlaps exp/LDS below)
    const int q0n = (kt == 35) ? 0 : (kt + 1) * 64;
    short8 nphi[4], nx[8];
#pragma unroll
    for (int nt = 0; nt < 4; nt++)
      nphi[nt] = *reinterpret_cast<const short8*>(
          phbase + (size_t)(q0n + nt * 16 + l15) * C2 + quad * 8);
#pragma unroll
    for (int nt = 0; nt < 4; nt++)
#pragma unroll
      for (int ks = 0; ks < 2; ks++)
        nx[nt * 2 + ks] = *reinterpret_cast<const short8*>(
            xbase + (size_t)(nt * 16 + l15) * PP + q0n + ks * 32 + quad * 8);

    // ---- w = exp2(S); accumulate l; stash w (bf16) to per-wave LDS
#pragma unroll
    for (int nt = 0; nt < 4; nt++) {
#pragma unroll
      for (int r = 0; r < 4; r++) {
        float w = EXP2(s_acc[nt][r]);
        l_acc[r] += w;
        W_lds[wv][quad * 4 + r][nt * 16 + l15] = f2bf(w);
      }
    }
    // ---- read W back as A-frags (same wave: ds ordering suffices)
    short8 a_w[2];
#pragma unroll
    for (int ks = 0; ks < 2; ks++)
      a_w[ks] = *reinterpret_cast<const short8*>(
          &W_lds[wv][l15][ks * 32 + quad * 8]);
    // ---- O += W . x^T   (K=64 keys -> 2 steps per ch-ntile)
#pragma unroll
    for (int nt = 0; nt < 4; nt++) {
      O[nt] = __builtin_amdgcn_mfma_f32_16x16x32_bf16(a_w[0], bx[nt * 2 + 0],
                                                      O[nt], 0, 0, 0);
      O[nt] = __builtin_amdgcn_mfma_f32_16x16x32_bf16(a_w[1], bx[nt * 2 + 1],
                                                      O[nt], 0, 0, 0);
    }
    // ---- rotate prefetch
#pragma unroll
    for (int nt = 0; nt < 4; nt++) bphi[nt] = nphi[nt];
#pragma unroll
    for (int i = 0; i < 8; i++) bx[i] = nx[i];
  }

  // ---- l: reduce over the 16-lane column group (rows = quad*4+reg)
#pragma unroll
  for (int r = 0; r < 4; r++) {
    float v = l_acc[r];
    v += __shfl_xor(v, 1);
    v += __shfl_xor(v, 2);
    v += __shfl_xor(v, 4);
    v += __shfl_xor(v, 8);
    l_acc[r] = 1.f / v;
  }
#pragma unroll
  for (int nt = 0; nt < 4; nt++)
#pragma unroll
    for (int r = 0; r < 4; r++) O[nt][r] *= l_acc[r];

  // ---- out-projection: D2[p][co] = f[p][c] . ow[co][c]
  // f C->A round trip through the same per-wave LDS slab
#pragma unroll
  for (int nt = 0; nt < 4; nt++)
#pragma unroll
    for (int r = 0; r < 4; r++)
      W_lds[wv][quad * 4 + r][nt * 16 + l15] = f2bf(O[nt][r]);
  short8 a_f[2];
#pragma unroll
  for (int ks = 0; ks < 2; ks++)
    a_f[ks] =
        *reinterpret_cast<const short8*>(&W_lds[wv][l15][ks * 32 + quad * 8]);

  float4v D2[4] = {zero, zero, zero, zero};
#pragma unroll
  for (int nt2 = 0; nt2 < 4; nt2++) {
#pragma unroll
    for (int ks = 0; ks < 2; ks++) {
      short8 bow;
      const float* wrow = ow + (size_t)(nt2 * 16 + l15) * CC + ks * 32 + quad * 8;
      float4 u0 = *reinterpret_cast<const float4*>(wrow);
      float4 u1 = *reinterpret_cast<const float4*>(wrow + 4);
      bow[0] = f2bf(u0.x); bow[1] = f2bf(u0.y);
      bow[2] = f2bf(u0.z); bow[3] = f2bf(u0.w);
      bow[4] = f2bf(u1.x); bow[5] = f2bf(u1.y);
      bow[6] = f2bf(u1.z); bow[7] = f2bf(u1.w);
      D2[nt2] =
          __builtin_amdgcn_mfma_f32_16x16x32_bf16(a_f[ks], bow, D2[nt2], 0, 0, 0);
    }
  }

  // ---- stage [co][p] in LDS, then coalesced float4 stores with residual
#pragma unroll
  for (int nt2 = 0; nt2 < 4; nt2++)
#pragma unroll
    for (int r = 0; r < 4; r++)
      out_s[nt2 * 16 + l15][wv * 16 + quad * 4 + r] = D2[nt2][r];
  __syncthreads();

  const int co = tid >> 2;
  const int psub = (tid & 3) * 16;
  const size_t gbase =
      ((size_t)(b * CC + co) * TT + t) * PP + ptile * 64 + psub;
#pragma unroll
  for (int j = 0; j < 4; j++) {
    float4 v = *reinterpret_cast<const float4*>(&out_s[co][psub + j * 4]);
    float4 xr = *reinterpret_cast<const float4*>(&x[gbase + j * 4]);
    v.x += xr.x; v.y += xr.y; v.z += xr.z; v.w += xr.w;
    *reinterpret_cast<float4*>(&out[gbase + j * 4]) = v;
  }
}

extern "C" void kernel_launch(void* const* d_in, const int* in_sizes, int n_in,
                              void* d_out, int out_size, void* d_ws,
                              size_t ws_size, hipStream_t stream) {
  (void)in_sizes; (void)n_in; (void)out_size; (void)ws_size;
  const float* x = (const float*)d_in[0];
  const float* tw = (const float*)d_in[1];
  const float* pw = (const float*)d_in[2];
  const float* ow = (const float*)d_in[3];
  float* out = (float*)d_out;

  short* thb = (short*)d_ws;                      // [BT][PP][32] bf16
  short* phb = thb + (size_t)BT * PP * C2;        // [BT][PP][32] bf16
  short* xb = phb + (size_t)BT * PP * C2;         // [BT][CC][PP] bf16
  // total ws use: 9.44 MB (<< available; prior NQ=4 path needed 48.5 MB)

  k_prep<<<dim3(9, BT), 256, 0, stream>>>(x, tw, pw, thb, phb, xb);
  k_attn_mfma<<<dim3(36, BT), 256, 0, stream>>>(x, thb, phb, xb, ow, out);
}